// Round 1
// baseline (94.449 us; speedup 1.0000x reference)
//
#include <hip/hip_runtime.h>

// Problem geometry (fixed by setup_inputs: B=32, S=8192, F=4, H=256, W=64)
#define S 8192
#define H 256
#define W 64
#define TILE 256
#define NTILES (S / TILE)   // 32

// np.nan_to_num semantics: nan->0, +inf->FLT_MAX, -inf->-FLT_MAX
__device__ __forceinline__ float nan2num(float v) {
    const float FMAX = 3.4028234663852886e38f;
    if (v != v) return 0.0f;
    if (v > FMAX) return FMAX;
    if (v < -FMAX) return -FMAX;
    return v;
}

__global__ __launch_bounds__(256) void vol_fused(
    const float4* __restrict__ x,     // (B,S,4) rows as float4 {open,high,low,close}
    const float*  __restrict__ lin_w, // (H,3)
    const float*  __restrict__ lin_b, // (H)
    float4*       __restrict__ out)   // (B,S,H) as float4
{
    __shared__ float s_close[TILE + W];       // need 319
    __shared__ float s_r[TILE + W - 2];       // 318 log-returns
    __shared__ float s_m0[TILE];
    __shared__ float s_m1[TILE];
    __shared__ float s_m2[TILE];

    const int tid = threadIdx.x;
    const int b   = blockIdx.x / NTILES;
    const int T0  = (blockIdx.x % NTILES) * TILE;

    const float4* xb = x + (size_t)b * S;

    // ---- stage close[j], j = T0-64 .. T0+254 (319 values), clamp j<0 (unused lanes) ----
    {
        int j0 = T0 - W + tid;
        s_close[tid] = xb[j0 < 0 ? 0 : j0].w;
        if (tid < W - 1) {                     // tid < 63 -> indices 256..318
            int j1 = T0 + (TILE - W) + tid;    // T0+192+tid <= T0+254 < S
            s_close[TILE + tid] = xb[j1].w;
        }
    }
    __syncthreads();

    // ---- r[k] = log(close[k+1]/close[k] + 1e-8), k in [0,318) ----
    s_r[tid] = logf(s_close[tid + 1] / s_close[tid] + 1e-8f);
    if (tid < TILE + W - 2 - TILE) {           // tid < 62 -> k = 256..317
        int k = TILE + tid;
        s_r[k] = logf(s_close[k + 1] / s_close[k] + 1e-8f);
    }
    __syncthreads();

    // ---- per-t measures: window r[t-64 .. t-2] == s_r[tid .. tid+62] ----
    {
        const float inv_n = 1.0f / 63.0f;      // W-1 samples
        float sum = 0.0f;
        for (int k = 0; k < W - 1; ++k) sum += s_r[tid + k];
        const float mean = sum * inv_n;
        float sd = 0.0f, sq = 0.0f;
        for (int k = 0; k < W - 1; ++k) {
            float v = s_r[tid + k];
            float d = v - mean;
            sd += d * d;                       // for std (ddof=1), two-pass
            sq += v * v;                       // for mean(rw^2)
        }

        float m0 = 0.0f, m1 = 0.0f, m2 = 0.0f;
        const int t = T0 + tid;
        if (t >= W) {
            float4 hv  = xb[t];                // y=high, z=low
            float lhl  = logf(hv.y / hv.z + 1e-8f);
            m0 = sqrtf(sd * (1.0f / 62.0f));   // ddof=1
            // gk = sqrt(0.5*lhl^2 - (2ln2-1)*mean(r^2)); negative/nan arg -> 0 (nan_to_num)
            float arg = 0.5f * lhl * lhl - 0.3862943611198906f * (sq * inv_n);
            m1 = (arg >= 0.0f) ? sqrtf(arg) : 0.0f;
            // pk = sqrt(lhl^2 / (4 ln2))
            m2 = sqrtf(lhl * lhl * 0.3606737602222409f);
            m0 = nan2num(m0); m1 = nan2num(m1); m2 = nan2num(m2);
        }
        s_m0[tid] = m0; s_m1[tid] = m1; s_m2[tid] = m2;
    }
    __syncthreads();

    // ---- write phase: each wave owns one t-row; 64 lanes x float4 = 1KiB/row ----
    const int hq = tid & 63;                   // float4 column index (h = hq*4)
    const int wv = tid >> 6;                   // wave id 0..3
    const int h0 = hq * 4;

    const float wa0 = lin_w[(h0+0)*3+0], wb0 = lin_w[(h0+0)*3+1], wc0 = lin_w[(h0+0)*3+2];
    const float wa1 = lin_w[(h0+1)*3+0], wb1 = lin_w[(h0+1)*3+1], wc1 = lin_w[(h0+1)*3+2];
    const float wa2 = lin_w[(h0+2)*3+0], wb2 = lin_w[(h0+2)*3+1], wc2 = lin_w[(h0+2)*3+2];
    const float wa3 = lin_w[(h0+3)*3+0], wb3 = lin_w[(h0+3)*3+1], wc3 = lin_w[(h0+3)*3+2];
    const float4 bv = ((const float4*)lin_b)[hq];

    float4* ob = out + (size_t)(b * S + T0) * (H / 4) + hq;

    #pragma unroll 4
    for (int it = 0; it < TILE / 4; ++it) {
        const int tl = (it << 2) + wv;
        const float m0 = s_m0[tl], m1 = s_m1[tl], m2 = s_m2[tl];
        float4 o;
        o.x = fmaxf(0.0f, fmaf(m0, wa0, fmaf(m1, wb0, fmaf(m2, wc0, bv.x))));
        o.y = fmaxf(0.0f, fmaf(m0, wa1, fmaf(m1, wb1, fmaf(m2, wc1, bv.y))));
        o.z = fmaxf(0.0f, fmaf(m0, wa2, fmaf(m1, wb2, fmaf(m2, wc2, bv.z))));
        o.w = fmaxf(0.0f, fmaf(m0, wa3, fmaf(m1, wb3, fmaf(m2, wc3, bv.w))));
        ob[(size_t)tl * (H / 4)] = o;
    }
}

extern "C" void kernel_launch(void* const* d_in, const int* in_sizes, int n_in,
                              void* d_out, int out_size, void* d_ws, size_t ws_size,
                              hipStream_t stream) {
    const float4* x  = (const float4*)d_in[0];
    const float*  lw = (const float*)d_in[1];
    const float*  lb = (const float*)d_in[2];
    float4* o = (float4*)d_out;

    const int B = in_sizes[0] / (S * 4);       // 32
    dim3 grid(B * NTILES), block(256);
    hipLaunchKernelGGL(vol_fused, grid, block, 0, stream, x, lw, lb, o);
}

// Round 2
// 62.182 us; speedup vs baseline: 1.5189x; 1.5189x over previous
//
#include <hip/hip_runtime.h>

// Problem geometry (fixed by setup_inputs: B=32, S=8192, F=4, H=256, W=64)
#define S 8192
#define H 256
#define W 64
#define TILE 256
#define NTILES (S / TILE)   // 32
#define RPB 128             // rows per block in write kernel

typedef float v4f __attribute__((ext_vector_type(4)));

// np.nan_to_num semantics: nan->0, +inf->FLT_MAX, -inf->-FLT_MAX
__device__ __forceinline__ float nan2num(float v) {
    const float FMAX = 3.4028234663852886e38f;
    if (v != v) return 0.0f;
    if (v > FMAX) return FMAX;
    if (v < -FMAX) return -FMAX;
    return v;
}

// ---------------- Kernel 1: measures (B,S) -> float4{std,gk,pk,0} in d_ws ----
__global__ __launch_bounds__(256) void vol_measures(
    const float4* __restrict__ x,     // (B,S,4) rows {open,high,low,close}
    v4f*          __restrict__ m)     // (B*S) float4 measures
{
    __shared__ float s_close[TILE + W];       // 319
    __shared__ float s_r[TILE + W - 2];       // 318 log-returns

    const int tid = threadIdx.x;
    const int b   = blockIdx.x / NTILES;
    const int T0  = (blockIdx.x % NTILES) * TILE;

    const float4* xb = x + (size_t)b * S;

    // stage close[j], j = T0-64 .. T0+254 (clamp j<0; those lanes' output is 0 anyway)
    {
        int j0 = T0 - W + tid;
        s_close[tid] = xb[j0 < 0 ? 0 : j0].w;
        if (tid < W - 1) {
            int j1 = T0 + (TILE - W) + tid;    // T0+192+tid <= T0+254 < S
            s_close[TILE + tid] = xb[j1].w;
        }
    }
    __syncthreads();

    // r[k] = log(close[k+1]/close[k] + 1e-8), local k in [0,318)
    s_r[tid] = logf(s_close[tid + 1] / s_close[tid] + 1e-8f);
    if (tid < 62) {
        int k = TILE + tid;
        s_r[k] = logf(s_close[k + 1] / s_close[k] + 1e-8f);
    }
    __syncthreads();

    // window for t = T0+tid is s_r[tid .. tid+62] (63 samples)
    const float inv_n = 1.0f / 63.0f;
    float sum = 0.0f;
    for (int k = 0; k < W - 1; ++k) sum += s_r[tid + k];
    const float mean = sum * inv_n;
    float sd = 0.0f, sq = 0.0f;
    for (int k = 0; k < W - 1; ++k) {
        float v = s_r[tid + k];
        float d = v - mean;
        sd += d * d;
        sq += v * v;
    }

    float m0 = 0.0f, m1 = 0.0f, m2 = 0.0f;
    const int t = T0 + tid;
    if (t >= W) {
        float4 hv  = xb[t];                    // y=high, z=low
        float lhl  = logf(hv.y / hv.z + 1e-8f);
        m0 = sqrtf(sd * (1.0f / 62.0f));       // std, ddof=1
        float arg = 0.5f * lhl * lhl - 0.3862943611198906f * (sq * inv_n);
        m1 = (arg >= 0.0f) ? sqrtf(arg) : 0.0f;            // gk (nan->0)
        m2 = sqrtf(lhl * lhl * 0.3606737602222409f);       // pk
        m0 = nan2num(m0); m1 = nan2num(m1); m2 = nan2num(m2);
    }
    v4f mv; mv.x = m0; mv.y = m1; mv.z = m2; mv.w = 0.0f;
    m[(size_t)b * S + t] = mv;                 // wave writes 1KiB coalesced
}

// ---------------- Kernel 2: pure streaming broadcast-write ------------------
__global__ __launch_bounds__(256) void vol_write(
    const v4f*  __restrict__ m,       // (B*S) measures
    const float* __restrict__ lin_w,  // (H,3)
    const float* __restrict__ lin_b,  // (H)
    v4f*        __restrict__ out)     // (B*S, H/4)
{
    const int tid = threadIdx.x;
    const int hq  = tid & 63;                  // float4 column (h = hq*4)
    const int wv  = tid >> 6;                  // wave id 0..3
    const int h0  = hq * 4;

    const float wa0 = lin_w[(h0+0)*3+0], wb0 = lin_w[(h0+0)*3+1], wc0 = lin_w[(h0+0)*3+2];
    const float wa1 = lin_w[(h0+1)*3+0], wb1 = lin_w[(h0+1)*3+1], wc1 = lin_w[(h0+1)*3+2];
    const float wa2 = lin_w[(h0+2)*3+0], wb2 = lin_w[(h0+2)*3+1], wc2 = lin_w[(h0+2)*3+2];
    const float wa3 = lin_w[(h0+3)*3+0], wb3 = lin_w[(h0+3)*3+1], wc3 = lin_w[(h0+3)*3+2];
    const v4f bv = ((const v4f*)lin_b)[hq];

    const size_t row0 = (size_t)blockIdx.x * RPB + wv;
    const v4f* mp = m + row0;
    v4f* op = out + row0 * (H / 4) + hq;

    #pragma unroll 4
    for (int i = 0; i < RPB / 4; ++i) {
        v4f mv = mp[(size_t)i * 4];            // same addr across wave -> broadcast
        v4f o;
        o.x = fmaxf(0.0f, fmaf(mv.x, wa0, fmaf(mv.y, wb0, fmaf(mv.z, wc0, bv.x))));
        o.y = fmaxf(0.0f, fmaf(mv.x, wa1, fmaf(mv.y, wb1, fmaf(mv.z, wc1, bv.y))));
        o.z = fmaxf(0.0f, fmaf(mv.x, wa2, fmaf(mv.y, wb2, fmaf(mv.z, wc2, bv.z))));
        o.w = fmaxf(0.0f, fmaf(mv.x, wa3, fmaf(mv.y, wb3, fmaf(mv.z, wc3, bv.w))));
        __builtin_nontemporal_store(o, op + (size_t)i * 4 * (H / 4));
    }
}

// ---------------- Fallback: original fused kernel (if ws too small) ---------
__global__ __launch_bounds__(256) void vol_fused(
    const float4* __restrict__ x, const float* __restrict__ lin_w,
    const float* __restrict__ lin_b, float4* __restrict__ out)
{
    __shared__ float s_close[TILE + W];
    __shared__ float s_r[TILE + W - 2];
    __shared__ float s_m0[TILE];
    __shared__ float s_m1[TILE];
    __shared__ float s_m2[TILE];

    const int tid = threadIdx.x;
    const int b   = blockIdx.x / NTILES;
    const int T0  = (blockIdx.x % NTILES) * TILE;
    const float4* xb = x + (size_t)b * S;

    {
        int j0 = T0 - W + tid;
        s_close[tid] = xb[j0 < 0 ? 0 : j0].w;
        if (tid < W - 1) s_close[TILE + tid] = xb[T0 + (TILE - W) + tid].w;
    }
    __syncthreads();
    s_r[tid] = logf(s_close[tid + 1] / s_close[tid] + 1e-8f);
    if (tid < 62) { int k = TILE + tid; s_r[k] = logf(s_close[k + 1] / s_close[k] + 1e-8f); }
    __syncthreads();
    {
        const float inv_n = 1.0f / 63.0f;
        float sum = 0.0f;
        for (int k = 0; k < W - 1; ++k) sum += s_r[tid + k];
        const float mean = sum * inv_n;
        float sd = 0.0f, sq = 0.0f;
        for (int k = 0; k < W - 1; ++k) {
            float v = s_r[tid + k]; float d = v - mean; sd += d * d; sq += v * v;
        }
        float m0 = 0, m1 = 0, m2 = 0;
        const int t = T0 + tid;
        if (t >= W) {
            float4 hv = xb[t];
            float lhl = logf(hv.y / hv.z + 1e-8f);
            m0 = sqrtf(sd * (1.0f / 62.0f));
            float arg = 0.5f * lhl * lhl - 0.3862943611198906f * (sq * inv_n);
            m1 = (arg >= 0.0f) ? sqrtf(arg) : 0.0f;
            m2 = sqrtf(lhl * lhl * 0.3606737602222409f);
            m0 = nan2num(m0); m1 = nan2num(m1); m2 = nan2num(m2);
        }
        s_m0[tid] = m0; s_m1[tid] = m1; s_m2[tid] = m2;
    }
    __syncthreads();
    const int hq = tid & 63, wv = tid >> 6, h0 = hq * 4;
    const float wa0 = lin_w[(h0+0)*3+0], wb0 = lin_w[(h0+0)*3+1], wc0 = lin_w[(h0+0)*3+2];
    const float wa1 = lin_w[(h0+1)*3+0], wb1 = lin_w[(h0+1)*3+1], wc1 = lin_w[(h0+1)*3+2];
    const float wa2 = lin_w[(h0+2)*3+0], wb2 = lin_w[(h0+2)*3+1], wc2 = lin_w[(h0+2)*3+2];
    const float wa3 = lin_w[(h0+3)*3+0], wb3 = lin_w[(h0+3)*3+1], wc3 = lin_w[(h0+3)*3+2];
    const float4 bv = ((const float4*)lin_b)[hq];
    float4* ob = out + (size_t)(b * S + T0) * (H / 4) + hq;
    #pragma unroll 4
    for (int it = 0; it < TILE / 4; ++it) {
        const int tl = (it << 2) + wv;
        const float m0 = s_m0[tl], m1 = s_m1[tl], m2 = s_m2[tl];
        float4 o;
        o.x = fmaxf(0.0f, fmaf(m0, wa0, fmaf(m1, wb0, fmaf(m2, wc0, bv.x))));
        o.y = fmaxf(0.0f, fmaf(m0, wa1, fmaf(m1, wb1, fmaf(m2, wc1, bv.y))));
        o.z = fmaxf(0.0f, fmaf(m0, wa2, fmaf(m1, wb2, fmaf(m2, wc2, bv.z))));
        o.w = fmaxf(0.0f, fmaf(m0, wa3, fmaf(m1, wb3, fmaf(m2, wc3, bv.w))));
        ob[(size_t)tl * (H / 4)] = o;
    }
}

extern "C" void kernel_launch(void* const* d_in, const int* in_sizes, int n_in,
                              void* d_out, int out_size, void* d_ws, size_t ws_size,
                              hipStream_t stream) {
    const float4* x  = (const float4*)d_in[0];
    const float*  lw = (const float*)d_in[1];
    const float*  lb = (const float*)d_in[2];

    const int B = in_sizes[0] / (S * 4);       // 32
    const size_t rows = (size_t)B * S;         // 262144
    const size_t need = rows * sizeof(v4f);    // 4 MiB

    if (ws_size >= need) {
        v4f* m = (v4f*)d_ws;
        hipLaunchKernelGGL(vol_measures, dim3(B * NTILES), dim3(256), 0, stream,
                           x, m);
        hipLaunchKernelGGL(vol_write, dim3((unsigned)(rows / RPB)), dim3(256), 0, stream,
                           m, lw, lb, (v4f*)d_out);
    } else {
        hipLaunchKernelGGL(vol_fused, dim3(B * NTILES), dim3(256), 0, stream,
                           x, lw, lb, (float4*)d_out);
    }
}

// Round 4
// 50.046 us; speedup vs baseline: 1.8872x; 1.2425x over previous
//
#include <hip/hip_runtime.h>

// Problem geometry (fixed by setup_inputs: B=32, S=8192, F=4, H=256, W=64)
#define S 8192
#define H 256
#define W 64
#define RPB 128             // rows (time steps) per block

typedef float v4f __attribute__((ext_vector_type(4)));

// np.nan_to_num semantics: nan->0, +inf->FLT_MAX, -inf->-FLT_MAX
__device__ __forceinline__ float nan2num(float v) {
    const float FMAX = 3.4028234663852886e38f;
    if (v != v) return 0.0f;
    if (v > FMAX) return FMAX;
    if (v < -FMAX) return -FMAX;
    return v;
}

// Single self-contained kernel: each block computes measures for its 128 rows
// (redundant 64-row halo vs neighbor blocks — trivial math) and streams the
// 128x256 fp32 output tile with cached stores. No workspace, no 2nd kernel.
__global__ __launch_bounds__(256, 8) void vol_one(
    const float4* __restrict__ x,     // (B,S,4) rows {open,high,low,close}
    const float*  __restrict__ lin_w, // (H,3)
    const float*  __restrict__ lin_b, // (H)
    v4f*          __restrict__ out)   // (B*S, H/4)
{
    __shared__ float s_close[RPB + W];        // 192
    __shared__ float s_r[RPB + W - 1];        // 191 log-returns
    __shared__ float s_m0[RPB];
    __shared__ float s_m1[RPB];
    __shared__ float s_m2[RPB];

    const int tid = threadIdx.x;
    const size_t row0 = (size_t)blockIdx.x * RPB;   // global flattened row
    const int b  = (int)(row0 / S);
    const int s0 = (int)(row0 % S);                 // RPB divides S -> block within one b

    const float4* xb = x + (size_t)b * S;

    // stage close[s0-64 .. s0+127] (192 values; clamp <0, those rows output 0 anyway)
    if (tid < RPB + W) {
        int j = s0 - W + tid;
        s_close[tid] = xb[j < 0 ? 0 : j].w;
    }
    __syncthreads();

    // r[k] = log(close[k+1]/close[k] + 1e-8), local k in [0,191)
    if (tid < RPB + W - 1) {
        s_r[tid] = logf(s_close[tid + 1] / s_close[tid] + 1e-8f);
    }
    __syncthreads();

    // measures for row t = s0+tid: window = s_r[tid .. tid+62] (63 samples)
    if (tid < RPB) {
        const float inv_n = 1.0f / 63.0f;
        float sum = 0.0f;
        for (int k = 0; k < W - 1; ++k) sum += s_r[tid + k];
        const float mean = sum * inv_n;
        float sd = 0.0f, sq = 0.0f;
        for (int k = 0; k < W - 1; ++k) {
            float v = s_r[tid + k];
            float d = v - mean;
            sd += d * d;
            sq += v * v;
        }
        float m0 = 0.0f, m1 = 0.0f, m2 = 0.0f;
        const int t = s0 + tid;
        if (t >= W) {
            float4 hv  = xb[t];                     // y=high, z=low
            float lhl  = logf(hv.y / hv.z + 1e-8f);
            m0 = sqrtf(sd * (1.0f / 62.0f));        // std, ddof=1
            float arg = 0.5f * lhl * lhl - 0.3862943611198906f * (sq * inv_n);
            m1 = (arg >= 0.0f) ? sqrtf(arg) : 0.0f; // gk (nan->0)
            m2 = sqrtf(lhl * lhl * 0.3606737602222409f);  // pk
            m0 = nan2num(m0); m1 = nan2num(m1); m2 = nan2num(m2);
        }
        s_m0[tid] = m0; s_m1[tid] = m1; s_m2[tid] = m2;
    }
    __syncthreads();

    // write phase: wave wv owns rows tl = 4*i+wv; 64 lanes x float4 = 1KiB/row
    const int hq = tid & 63;                   // float4 column (h = hq*4)
    const int wv = tid >> 6;                   // wave id 0..3
    const int h0 = hq * 4;

    const float wa0 = lin_w[(h0+0)*3+0], wb0 = lin_w[(h0+0)*3+1], wc0 = lin_w[(h0+0)*3+2];
    const float wa1 = lin_w[(h0+1)*3+0], wb1 = lin_w[(h0+1)*3+1], wc1 = lin_w[(h0+1)*3+2];
    const float wa2 = lin_w[(h0+2)*3+0], wb2 = lin_w[(h0+2)*3+1], wc2 = lin_w[(h0+2)*3+2];
    const float wa3 = lin_w[(h0+3)*3+0], wb3 = lin_w[(h0+3)*3+1], wc3 = lin_w[(h0+3)*3+2];
    const v4f bv = ((const v4f*)lin_b)[hq];

    v4f* op = out + (row0 + wv) * (H / 4) + hq;

    #pragma unroll 4
    for (int i = 0; i < RPB / 4; ++i) {
        const int tl = (i << 2) + wv;
        const float m0 = s_m0[tl], m1 = s_m1[tl], m2 = s_m2[tl];  // LDS broadcast
        v4f o;
        o.x = fmaxf(0.0f, fmaf(m0, wa0, fmaf(m1, wb0, fmaf(m2, wc0, bv.x))));
        o.y = fmaxf(0.0f, fmaf(m0, wa1, fmaf(m1, wb1, fmaf(m2, wc1, bv.y))));
        o.z = fmaxf(0.0f, fmaf(m0, wa2, fmaf(m1, wb2, fmaf(m2, wc2, bv.z))));
        o.w = fmaxf(0.0f, fmaf(m0, wa3, fmaf(m1, wb3, fmaf(m2, wc3, bv.w))));
        op[(size_t)i * 4 * (H / 4)] = o;       // cached store
    }
}

extern "C" void kernel_launch(void* const* d_in, const int* in_sizes, int n_in,
                              void* d_out, int out_size, void* d_ws, size_t ws_size,
                              hipStream_t stream) {
    const float4* x  = (const float4*)d_in[0];
    const float*  lw = (const float*)d_in[1];
    const float*  lb = (const float*)d_in[2];

    const int B = in_sizes[0] / (S * 4);       // 32
    const size_t rows = (size_t)B * S;         // 262144

    hipLaunchKernelGGL(vol_one, dim3((unsigned)(rows / RPB)), dim3(256), 0, stream,
                       x, lw, lb, (v4f*)d_out);
}

// Round 5
// 46.766 us; speedup vs baseline: 2.0196x; 1.0701x over previous
//
#include <hip/hip_runtime.h>

// Problem geometry (fixed by setup_inputs: B=32, S=8192, F=4, H=256, W=64)
#define S 8192
#define H 256
#define W 64
#define RPB 64              // rows (time steps) per block -> 4096 blocks, 2 generations

typedef float v4f __attribute__((ext_vector_type(4)));

// np.nan_to_num semantics: nan->0, +inf->FLT_MAX, -inf->-FLT_MAX
__device__ __forceinline__ float nan2num(float v) {
    const float FMAX = 3.4028234663852886e38f;
    if (v != v) return 0.0f;
    if (v > FMAX) return FMAX;
    if (v < -FMAX) return -FMAX;
    return v;
}

__global__ __launch_bounds__(256, 8) void vol_one(
    const float4* __restrict__ x,     // (B,S,4) rows {open,high,low,close}
    const float*  __restrict__ lin_w, // (H,3)
    const float*  __restrict__ lin_b, // (H)
    v4f*          __restrict__ out)   // (B*S, H/4)
{
    __shared__ float s_close[RPB + W];        // 128
    __shared__ float s_r[RPB + W - 1];        // 127 log-returns
    __shared__ float s_m0[RPB];
    __shared__ float s_m1[RPB];
    __shared__ float s_m2[RPB];

    const int tid = threadIdx.x;
    const size_t row0 = (size_t)blockIdx.x * RPB;   // global flattened row
    const int b  = (int)(row0 / S);
    const int s0 = (int)(row0 % S);                 // RPB | S -> block within one b

    const float4* xb = x + (size_t)b * S;

    // stage close[s0-64 .. s0+63] (128 values; clamp <0 -> those rows output bias-only)
    if (tid < RPB + W) {
        int j = s0 - W + tid;
        s_close[tid] = xb[j < 0 ? 0 : j].w;
    }
    __syncthreads();

    // r[k] = log(close[k+1]/close[k] + 1e-8), local k in [0,127)
    if (tid < RPB + W - 1) {
        s_r[tid] = logf(s_close[tid + 1] / s_close[tid] + 1e-8f);
    }
    __syncthreads();

    // measures for row t = s0+tid (tid<64): window = s_r[tid .. tid+62], 63 samples
    if (tid < RPB) {
        const float inv_n = 1.0f / 63.0f;
        float sum = 0.0f, sq = 0.0f;
        #pragma unroll 7
        for (int k = 0; k < W - 1; ++k) {
            float v = s_r[tid + k];
            sum += v;
            sq  = fmaf(v, v, sq);
        }
        const float mean = sum * inv_n;

        float m0 = 0.0f, m1 = 0.0f, m2 = 0.0f;
        const int t = s0 + tid;
        if (t >= W) {
            float4 hv  = xb[t];                     // y=high, z=low
            float lhl  = logf(hv.y / hv.z + 1e-8f);
            // var(ddof=1) = (sq - sum*mean) / 62  (one-pass form; threshold slack 22x)
            float var = (sq - sum * mean) * (1.0f / 62.0f);
            m0 = (var >= 0.0f) ? sqrtf(var) : 0.0f;
            float arg = 0.5f * lhl * lhl - 0.3862943611198906f * (sq * inv_n);
            m1 = (arg >= 0.0f) ? sqrtf(arg) : 0.0f; // gk (nan->0)
            m2 = sqrtf(lhl * lhl * 0.3606737602222409f);  // pk
            m0 = nan2num(m0); m1 = nan2num(m1); m2 = nan2num(m2);
        }
        s_m0[tid] = m0; s_m1[tid] = m1; s_m2[tid] = m2;
    }
    __syncthreads();

    // write phase: wave wv owns rows tl = 4*i+wv; 64 lanes x float4 = 1KiB/row
    const int hq = tid & 63;                   // float4 column (h = hq*4)
    const int wv = tid >> 6;                   // wave id 0..3
    const int h0 = hq * 4;

    const float wa0 = lin_w[(h0+0)*3+0], wb0 = lin_w[(h0+0)*3+1], wc0 = lin_w[(h0+0)*3+2];
    const float wa1 = lin_w[(h0+1)*3+0], wb1 = lin_w[(h0+1)*3+1], wc1 = lin_w[(h0+1)*3+2];
    const float wa2 = lin_w[(h0+2)*3+0], wb2 = lin_w[(h0+2)*3+1], wc2 = lin_w[(h0+2)*3+2];
    const float wa3 = lin_w[(h0+3)*3+0], wb3 = lin_w[(h0+3)*3+1], wc3 = lin_w[(h0+3)*3+2];
    const v4f bv = ((const v4f*)lin_b)[hq];

    v4f* op = out + (row0 + wv) * (H / 4) + hq;

    #pragma unroll 4
    for (int i = 0; i < RPB / 4; ++i) {
        const int tl = (i << 2) + wv;
        const float m0 = s_m0[tl], m1 = s_m1[tl], m2 = s_m2[tl];  // LDS broadcast
        v4f o;
        o.x = fmaxf(0.0f, fmaf(m0, wa0, fmaf(m1, wb0, fmaf(m2, wc0, bv.x))));
        o.y = fmaxf(0.0f, fmaf(m0, wa1, fmaf(m1, wb1, fmaf(m2, wc1, bv.y))));
        o.z = fmaxf(0.0f, fmaf(m0, wa2, fmaf(m1, wb2, fmaf(m2, wc2, bv.z))));
        o.w = fmaxf(0.0f, fmaf(m0, wa3, fmaf(m1, wb3, fmaf(m2, wc3, bv.w))));
        op[(size_t)i * 4 * (H / 4)] = o;       // cached store
    }
}

extern "C" void kernel_launch(void* const* d_in, const int* in_sizes, int n_in,
                              void* d_out, int out_size, void* d_ws, size_t ws_size,
                              hipStream_t stream) {
    const float4* x  = (const float4*)d_in[0];
    const float*  lw = (const float*)d_in[1];
    const float*  lb = (const float*)d_in[2];

    const int B = in_sizes[0] / (S * 4);       // 32
    const size_t rows = (size_t)B * S;         // 262144

    hipLaunchKernelGGL(vol_one, dim3((unsigned)(rows / RPB)), dim3(256), 0, stream,
                       x, lw, lb, (v4f*)d_out);
}

// Round 6
// 46.690 us; speedup vs baseline: 2.0229x; 1.0016x over previous
//
#include <hip/hip_runtime.h>

// Problem geometry (fixed by setup_inputs: B=32, S=8192, F=4, H=256, W=64)
#define S 8192
#define H 256
#define W 64
#define RPB 64              // rows per block -> 4096 blocks, 2 generations of 8/CU

typedef float v4f __attribute__((ext_vector_type(4)));

// np.nan_to_num semantics: nan->0, +inf->FLT_MAX, -inf->-FLT_MAX
__device__ __forceinline__ float nan2num(float v) {
    const float FMAX = 3.4028234663852886e38f;
    if (v != v) return 0.0f;
    if (v > FMAX) return FMAX;
    if (v < -FMAX) return -FMAX;
    return v;
}

__global__ __launch_bounds__(256, 8) void vol_one(
    const float4* __restrict__ x,     // (B,S,4) rows {open,high,low,close}
    const float*  __restrict__ lin_w, // (H,3)
    const float*  __restrict__ lin_b, // (H)
    v4f*          __restrict__ out)   // (B*S, H/4)
{
    __shared__ float s_r[RPB + W - 1];        // 127 log-returns
    __shared__ v4f   s_m[RPB];                // packed measures {std,gk,pk,0}

    const int tid = threadIdx.x;
    const size_t row0 = (size_t)blockIdx.x * RPB;   // global flattened row
    const int b  = (int)(row0 / S);
    const int s0 = (int)(row0 % S);                 // RPB | S -> block within one b

    const float4* xb = x + (size_t)b * S;

    // ---- phase 1: r[k] = log(close[j+1]/close[j] + 1e-8), j = s0-64+k, k in [0,127)
    // (j<0 only in s0==0 blocks, whose rows are all masked -> clamp is harmless)
    if (tid < RPB + W - 1) {
        int j = s0 - W + tid;
        if (j < 0) j = 0;
        float c0 = xb[j].w;
        float c1 = xb[j + 1].w;
        s_r[tid] = logf(c1 / c0 + 1e-8f);
    }
    __syncthreads();

    // ---- phase 2: 4-lane-split window reduction. row r = tid>>2, part p = tid&3.
    // window for row r = s_r[r .. r+62] (63 samples); lane p sums k = p*16 .. p*16+15
    // (k==63 masked to 0). Reduce across the 4 adjacent lanes via shfl_xor.
    {
        const int r = tid >> 2;
        const int p = tid & 3;
        const int k0 = p * 16;
        float sum = 0.0f, sq = 0.0f;
        #pragma unroll
        for (int i = 0; i < 16; ++i) {
            const int k = k0 + i;
            float v = s_r[r + k];              // r+k <= 63+63 = 126, in-bounds
            v = (k == 63) ? 0.0f : v;          // only p==3's last sample masked
            sum += v;
            sq  = fmaf(v, v, sq);
        }
        sum += __shfl_xor(sum, 1);
        sum += __shfl_xor(sum, 2);
        sq  += __shfl_xor(sq, 1);
        sq  += __shfl_xor(sq, 2);

        if (p == 0) {
            const float inv_n = 1.0f / 63.0f;
            float m0 = 0.0f, m1 = 0.0f, m2 = 0.0f;
            const int t = s0 + r;
            if (t >= W) {
                float4 hv  = xb[t];                     // y=high, z=low
                float lhl  = logf(hv.y / hv.z + 1e-8f);
                float mean = sum * inv_n;
                float var  = (sq - sum * mean) * (1.0f / 62.0f);  // ddof=1, one-pass
                m0 = (var >= 0.0f) ? sqrtf(var) : 0.0f;
                float arg = 0.5f * lhl * lhl - 0.3862943611198906f * (sq * inv_n);
                m1 = (arg >= 0.0f) ? sqrtf(arg) : 0.0f; // gk (nan->0)
                m2 = sqrtf(lhl * lhl * 0.3606737602222409f);      // pk
                m0 = nan2num(m0); m1 = nan2num(m1); m2 = nan2num(m2);
            }
            v4f mv; mv.x = m0; mv.y = m1; mv.z = m2; mv.w = 0.0f;
            s_m[r] = mv;
        }
    }
    __syncthreads();

    // ---- store phase: wave wv owns rows tl = 4*i+wv; 64 lanes x float4 = 1KiB/row
    const int hq = tid & 63;                   // float4 column (h = hq*4)
    const int wv = tid >> 6;                   // wave id 0..3
    const int h0 = hq * 4;

    const float wa0 = lin_w[(h0+0)*3+0], wb0 = lin_w[(h0+0)*3+1], wc0 = lin_w[(h0+0)*3+2];
    const float wa1 = lin_w[(h0+1)*3+0], wb1 = lin_w[(h0+1)*3+1], wc1 = lin_w[(h0+1)*3+2];
    const float wa2 = lin_w[(h0+2)*3+0], wb2 = lin_w[(h0+2)*3+1], wc2 = lin_w[(h0+2)*3+2];
    const float wa3 = lin_w[(h0+3)*3+0], wb3 = lin_w[(h0+3)*3+1], wc3 = lin_w[(h0+3)*3+2];
    const v4f bv = ((const v4f*)lin_b)[hq];

    v4f* op = out + (row0 + wv) * (H / 4) + hq;

    #pragma unroll 4
    for (int i = 0; i < RPB / 4; ++i) {
        const v4f mv = s_m[(i << 2) + wv];     // one ds_read_b128, wave-broadcast
        v4f o;
        o.x = fmaxf(0.0f, fmaf(mv.x, wa0, fmaf(mv.y, wb0, fmaf(mv.z, wc0, bv.x))));
        o.y = fmaxf(0.0f, fmaf(mv.x, wa1, fmaf(mv.y, wb1, fmaf(mv.z, wc1, bv.y))));
        o.z = fmaxf(0.0f, fmaf(mv.x, wa2, fmaf(mv.y, wb2, fmaf(mv.z, wc2, bv.z))));
        o.w = fmaxf(0.0f, fmaf(mv.x, wa3, fmaf(mv.y, wb3, fmaf(mv.z, wc3, bv.w))));
        op[(size_t)i * 4 * (H / 4)] = o;       // cached store
    }
}

extern "C" void kernel_launch(void* const* d_in, const int* in_sizes, int n_in,
                              void* d_out, int out_size, void* d_ws, size_t ws_size,
                              hipStream_t stream) {
    const float4* x  = (const float4*)d_in[0];
    const float*  lw = (const float*)d_in[1];
    const float*  lb = (const float*)d_in[2];

    const int B = in_sizes[0] / (S * 4);       // 32
    const size_t rows = (size_t)B * S;         // 262144

    hipLaunchKernelGGL(vol_one, dim3((unsigned)(rows / RPB)), dim3(256), 0, stream,
                       x, lw, lb, (v4f*)d_out);
}